// Round 1
// baseline (1530.038 us; speedup 1.0000x reference)
//
#include <hip/hip_runtime.h>
#include <hip/hip_bf16.h>

// Problem constants
#define TT   128
#define BB   256
#define WD   300
#define TD   64
#define RD   64
#define MM   512
#define GG   2560
#define K1P  960   // 940 padded to 960 (30 * 32)

typedef __attribute__((ext_vector_type(8))) short bf16x8;
typedef __attribute__((ext_vector_type(4))) short bf16x4;
typedef __attribute__((ext_vector_type(4))) float f32x4;

__device__ __forceinline__ float bf2f(unsigned short u){
  union { unsigned u; float f; } v; v.u = ((unsigned)u) << 16; return v.f;
}
__device__ __forceinline__ unsigned short f2bf(float f){
  union { float f; unsigned u; } v; v.f = f;
  unsigned r = v.u + 0x7fffu + ((v.u >> 16) & 1u);
  return (unsigned short)(r >> 16);
}
__device__ __forceinline__ float sigmoidf_(float x){ return 1.f/(1.f + __expf(-x)); }
__device__ __forceinline__ float tanhf_(float x){
  x = fminf(15.f, fmaxf(-15.f, x));
  float e = __expf(2.f*x);
  return (e - 1.f)/(e + 1.f);
}

// ---------------- staging kernels ----------------

// A_bf16[32768][960]: [word | tag | rel | k | 0pad] per row, bf16
__global__ __launch_bounds__(256) void stage_a(const float* __restrict__ word,
                                               const float* __restrict__ tag,
                                               const float* __restrict__ rel,
                                               const float* __restrict__ kin,
                                               unsigned short* __restrict__ A){
  long id = (long)blockIdx.x * 256 + threadIdx.x;     // chunk over 32768*120
  int row = (int)(id / 120);
  int c8  = (int)(id % 120) * 8;
  bf16x8 o;
  #pragma unroll
  for (int j = 0; j < 8; ++j){
    int col = c8 + j; float v;
    if      (col < 300) v = word[(long)row*300 + col];
    else if (col < 364) v = tag [(long)row*64  + col-300];
    else if (col < 428) v = rel [(long)row*64  + col-364];
    else if (col < 940) v = kin [(long)row*512 + col-428];
    else v = 0.f;
    o[j] = (short)f2bf(v);
  }
  *reinterpret_cast<bf16x8*>(A + (long)row*K1P + c8) = o;
}

// WT[2560][960] = stacked [Ww;Wt;Wr;Wk] transposed, bf16, zero pad k>=940
__global__ __launch_bounds__(256) void stage_wt(const float* __restrict__ Ww,
                                                const float* __restrict__ Wt,
                                                const float* __restrict__ Wr,
                                                const float* __restrict__ Wk,
                                                unsigned short* __restrict__ WT){
  long id = (long)blockIdx.x * 256 + threadIdx.x;   // 2560*960
  int kk = (int)(id % K1P);
  int n  = (int)(id / K1P);
  float v;
  if      (kk < 300) v = Ww[(long)kk*GG + n];
  else if (kk < 364) v = Wt[(long)(kk-300)*GG + n];
  else if (kk < 428) v = Wr[(long)(kk-364)*GG + n];
  else if (kk < 940) v = Wk[(long)(kk-428)*GG + n];
  else v = 0.f;
  WT[(long)n*K1P + kk] = f2bf(v);
}

// WhT[2560][512] = Wh transposed, bf16
__global__ __launch_bounds__(256) void stage_wht(const float* __restrict__ Wh,
                                                 unsigned short* __restrict__ WhT){
  long id = (long)blockIdx.x * 256 + threadIdx.x;   // 2560*512
  int kk = (int)(id % MM);
  int n  = (int)(id / MM);
  WhT[(long)n*MM + kk] = f2bf(Wh[(long)kk*GG + n]);
}

// h0 -> bf16 ping buffer, c0 -> fp32 working buffer
__global__ __launch_bounds__(256) void init_hc(const float* __restrict__ h0,
                                               const float* __restrict__ c0,
                                               unsigned short* __restrict__ hb,
                                               float* __restrict__ cb){
  int id = blockIdx.x * 256 + threadIdx.x;          // 131072
  hb[id] = f2bf(h0[id]);
  cb[id] = c0[id];
}

// ---------------- xp GEMM ----------------
// xp[t][g][b] (bf16) = A(32768x960) @ WT^T + bias ; 128x128 tile, BK=32
__global__ __launch_bounds__(256) void gemm_xp(const unsigned short* __restrict__ A,
                                               const unsigned short* __restrict__ WT,
                                               const float* __restrict__ bias,
                                               unsigned short* __restrict__ XP){
  constexpr int STR = 56;   // padded LDS row stride (elems): 112B = 7*16, conflict-light
  __shared__ unsigned short As[128*STR];
  __shared__ unsigned short Bs[128*STR];
  const int tid  = threadIdx.x;
  const int wave = tid >> 6, lane = tid & 63;
  const int wr   = wave >> 1, wc = wave & 1;
  const int lrow = lane & 15, lhi = lane >> 4;
  const long row0 = (long)blockIdx.x * 128;
  const long col0 = (long)blockIdx.y * 128;
  const int r1  = tid >> 2;            // 0..63
  const int ko1 = (tid & 3) * 8;       // 0,8,16,24
  f32x4 acc[4][4] = {};
  for (int ks = 0; ks < 30; ++ks){
    const int k0 = ks * 32;
    bf16x8 a0 = *reinterpret_cast<const bf16x8*>(A  + (row0 + r1     )*K1P + k0 + ko1);
    bf16x8 a1 = *reinterpret_cast<const bf16x8*>(A  + (row0 + r1 + 64)*K1P + k0 + ko1);
    bf16x8 b0 = *reinterpret_cast<const bf16x8*>(WT + (col0 + r1     )*K1P + k0 + ko1);
    bf16x8 b1 = *reinterpret_cast<const bf16x8*>(WT + (col0 + r1 + 64)*K1P + k0 + ko1);
    __syncthreads();
    *reinterpret_cast<bf16x8*>(As + (r1     )*STR + ko1) = a0;
    *reinterpret_cast<bf16x8*>(As + (r1 + 64)*STR + ko1) = a1;
    *reinterpret_cast<bf16x8*>(Bs + (r1     )*STR + ko1) = b0;
    *reinterpret_cast<bf16x8*>(Bs + (r1 + 64)*STR + ko1) = b1;
    __syncthreads();
    bf16x8 af[4], bfr[4];
    #pragma unroll
    for (int mi = 0; mi < 4; ++mi)
      af[mi] = *reinterpret_cast<const bf16x8*>(As + (wr*64 + mi*16 + lrow)*STR + lhi*8);
    #pragma unroll
    for (int ni = 0; ni < 4; ++ni)
      bfr[ni] = *reinterpret_cast<const bf16x8*>(Bs + (wc*64 + ni*16 + lrow)*STR + lhi*8);
    #pragma unroll
    for (int mi = 0; mi < 4; ++mi)
      #pragma unroll
      for (int ni = 0; ni < 4; ++ni)
        acc[mi][ni] = __builtin_amdgcn_mfma_f32_16x16x32_bf16(af[mi], bfr[ni], acc[mi][ni], 0, 0, 0);
  }
  // epilogue: + bias, store XP as [T][G][B] so step kernel gets 4 batch rows per 8B load
  const int t     = (int)(row0 >> 8);
  const int brow0 = (int)(row0 & 255);
  #pragma unroll
  for (int ni = 0; ni < 4; ++ni){
    const int col = (int)col0 + wc*64 + ni*16 + lrow;
    const float bv = bias[col];
    #pragma unroll
    for (int mi = 0; mi < 4; ++mi){
      const int b4 = brow0 + wr*64 + mi*16 + lhi*4;
      bf16x4 pk;
      #pragma unroll
      for (int j = 0; j < 4; ++j) pk[j] = (short)f2bf(acc[mi][ni][j] + bv);
      *reinterpret_cast<bf16x4*>(XP + ((long)t*GG + col)*BB + b4) = pk;
    }
  }
}

// ---------------- recurrence step ----------------
// grid (16,16): blockIdx.x -> 16 batch rows, blockIdx.y -> 32 m cols; 2 waves (16 cols each)
__global__ __launch_bounds__(128) void lstm_step(const unsigned short* __restrict__ XP,
                                                 const float* __restrict__ q,
                                                 const unsigned short* __restrict__ WhT,
                                                 const unsigned short* __restrict__ hcur,
                                                 unsigned short* __restrict__ hnxt,
                                                 float* __restrict__ cbuf,
                                                 float* __restrict__ out,
                                                 const int t, const int last){
  constexpr int SSTR = 536;  // 1072B = 67*16, conflict-free b128 row reads
  __shared__ unsigned short Hs[16*SSTR];
  const int tid  = threadIdx.x;
  const int wave = tid >> 6, lane = tid & 63;
  const int lrow = lane & 15, lhi = lane >> 4;
  const int b0 = blockIdx.x * 16;
  const int m0 = blockIdx.y * 32 + wave * 16;
  // stage h tile (16 rows x 512) to LDS
  #pragma unroll
  for (int i = 0; i < 8; ++i){
    int c = tid + i*128;
    int row = c >> 6, co = (c & 63) * 8;
    bf16x8 v = *reinterpret_cast<const bf16x8*>(hcur + (long)(b0 + row)*MM + co);
    *reinterpret_cast<bf16x8*>(Hs + row*SSTR + co) = v;
  }
  __syncthreads();
  f32x4 acc[5] = {};
  #pragma unroll
  for (int ks = 0; ks < 16; ++ks){
    const int k0 = ks * 32;
    bf16x8 af = *reinterpret_cast<const bf16x8*>(Hs + lrow*SSTR + k0 + lhi*8);
    #pragma unroll
    for (int j = 0; j < 5; ++j){
      const long n = (long)j*MM + m0 + lrow;
      bf16x8 bfr = *reinterpret_cast<const bf16x8*>(WhT + n*MM + k0 + lhi*8);
      acc[j] = __builtin_amdgcn_mfma_f32_16x16x32_bf16(af, bfr, acc[j], 0, 0, 0);
    }
  }
  // epilogue: gates + state update
  const int m = m0 + lrow;
  float gv[5][4];
  #pragma unroll
  for (int j = 0; j < 5; ++j){
    bf16x4 xv = *reinterpret_cast<const bf16x4*>(XP + ((long)t*GG + (long)j*MM + m)*BB + b0 + lhi*4);
    #pragma unroll
    for (int jj = 0; jj < 4; ++jj)
      gv[j][jj] = acc[j][jj] + bf2f((unsigned short)xv[jj]);
  }
  #pragma unroll
  for (int jj = 0; jj < 4; ++jj){
    const int r = b0 + lhi*4 + jj;
    const float i_ = sigmoidf_(gv[0][jj]);
    const float fd = sigmoidf_(gv[1][jj]);
    const float fl = sigmoidf_(gv[2][jj]);
    const float o_ = sigmoidf_(gv[3][jj]);
    const float u_ = tanhf_(gv[4][jj]);
    const float qv = q[((long)t*BB + r)*MM + m];
    const float cv = cbuf[(long)r*MM + m];
    const float cn = i_*u_ + fd*qv + fl*cv;
    const float hn = o_*tanhf_(cn);
    cbuf[(long)r*MM + m] = cn;
    hnxt[(long)r*MM + m] = f2bf(hn);
    if (last){
      out[(long)r*1024 + m]       = hn;
      out[(long)r*1024 + 512 + m] = cn;
    }
  }
}

extern "C" void kernel_launch(void* const* d_in, const int* in_sizes, int n_in,
                              void* d_out, int out_size, void* d_ws, size_t ws_size,
                              hipStream_t stream){
  (void)in_sizes; (void)n_in; (void)out_size; (void)ws_size;
  const float* word = (const float*)d_in[0];
  const float* tag  = (const float*)d_in[1];
  const float* rel  = (const float*)d_in[2];
  const float* kin  = (const float*)d_in[3];
  const float* q    = (const float*)d_in[4];
  const float* h0   = (const float*)d_in[5];
  const float* c0   = (const float*)d_in[6];
  const float* Ww   = (const float*)d_in[7];
  const float* Wt   = (const float*)d_in[8];
  const float* Wr   = (const float*)d_in[9];
  const float* Wk   = (const float*)d_in[10];
  const float* Wh   = (const float*)d_in[11];
  const float* bias = (const float*)d_in[12];
  float* out = (float*)d_out;

  char* ws = (char*)d_ws;
  size_t off = 0;
  auto alloc = [&](size_t bytes)->void*{
    void* p = ws + off; off = (off + bytes + 255) & ~(size_t)255; return p;
  };
  unsigned short* Abf = (unsigned short*)alloc((size_t)TT*BB*K1P*2);   // 62.9 MB
  unsigned short* WT  = (unsigned short*)alloc((size_t)GG*K1P*2);      // 4.9 MB
  unsigned short* WhT = (unsigned short*)alloc((size_t)GG*MM*2);       // 2.6 MB
  unsigned short* XP  = (unsigned short*)alloc((size_t)TT*BB*GG*2);    // 167.8 MB
  unsigned short* hb0 = (unsigned short*)alloc((size_t)BB*MM*2);
  unsigned short* hb1 = (unsigned short*)alloc((size_t)BB*MM*2);
  float*          cbuf= (float*)alloc((size_t)BB*MM*4);

  stage_a  <<<dim3((TT*BB*(K1P/8) + 255)/256), 256, 0, stream>>>(word, tag, rel, kin, Abf);
  stage_wt <<<dim3((GG*K1P + 255)/256),        256, 0, stream>>>(Ww, Wt, Wr, Wk, WT);
  stage_wht<<<dim3((GG*MM + 255)/256),         256, 0, stream>>>(Wh, WhT);
  init_hc  <<<dim3((BB*MM + 255)/256),         256, 0, stream>>>(h0, c0, hb0, cbuf);

  gemm_xp<<<dim3(TT*BB/128, GG/128), 256, 0, stream>>>(Abf, WT, bias, XP);

  for (int t = 0; t < TT; ++t){
    const unsigned short* hc = (t & 1) ? hb1 : hb0;
    unsigned short*       hn = (t & 1) ? hb0 : hb1;
    lstm_step<<<dim3(BB/16, MM/32), 128, 0, stream>>>(XP, q, WhT, hc, hn, cbuf, out, t, (t == TT-1) ? 1 : 0);
  }
}